// Round 1
// 12180.950 us; speedup vs baseline: 1.3747x; 1.3747x over previous
//
#include <hip/hip_runtime.h>
#include <hip/hip_bf16.h>

typedef __bf16 bf16x8 __attribute__((ext_vector_type(8)));
typedef __bf16 bf16x4 __attribute__((ext_vector_type(4)));
typedef float  f32x4  __attribute__((ext_vector_type(4)));

// Convert 8 consecutive fp32 -> bf16x8 fragment (16B-aligned source).
__device__ __forceinline__ bf16x8 cvt8(const float* p) {
    f32x4 a = *(const f32x4*)p;
    f32x4 b = *(const f32x4*)(p + 4);
    bf16x8 r;
    r[0] = (__bf16)a[0]; r[1] = (__bf16)a[1]; r[2] = (__bf16)a[2]; r[3] = (__bf16)a[3];
    r[4] = (__bf16)b[0]; r[5] = (__bf16)b[1]; r[6] = (__bf16)b[2]; r[7] = (__bf16)b[3];
    return r;
}

// ---------------------------------------------------------------------------
// B=64, T=512, I=1024, H=1024, 4H=4096.  ALL I/O IS FP32.
// PG (pre-gates, bf16, (T,B,4H) = 256 MiB) lives in the FIRST 256 MiB of
// d_out (nothing writes d_out until k_finalize/k_tail at the end).
// ws: h_hist bf16 (T,B,H) 64 MiB | buf0,buf1 bf16 (2cells x 64 x 1024) |
//     cf,cb fp32 | barrier counters
// ---------------------------------------------------------------------------

__global__ __launch_bounds__(256) void k_init(
    const float* __restrict__ h0f, const float* __restrict__ h0b,
    __bf16* __restrict__ buf0, unsigned* __restrict__ bar)
{
    int i = blockIdx.x * 256 + threadIdx.x;   // 65536
    buf0[i]         = (__bf16)h0f[i];
    buf0[65536 + i] = (__bf16)h0b[i];
    if (i == 0) { bar[0] = 0u; bar[32] = 0u; }
}

// PG[t][b][gc] = bias[gc] + sum_i x[b][t][i] * Wih[gc][i]   (bf16 MFMA, fp32 acc)
// grid (64 colblocks, 512 t), 4 waves; wave w -> 16 cols; inline fp32->bf16 cvt.
__global__ __launch_bounds__(256) void k_pregemm(
    const float* __restrict__ x,     // (B,T,I) fp32
    const float* __restrict__ Wih,   // (4H,I) fp32
    const float* __restrict__ bih, const float* __restrict__ bhh,
    __bf16* __restrict__ PG)
{
    const int t    = blockIdx.y;
    const int w    = threadIdx.x >> 6;
    const int lane = threadIdx.x & 63;
    const int m    = lane & 15;
    const int quad = lane >> 4;
    const int col  = blockIdx.x * 64 + w * 16 + m;

    f32x4 acc[4] = {};
    const float* Brow = Wih + col * 1024 + quad * 8;
    const float* Arow = x + (m * 512 + t) * 1024 + quad * 8;  // row b = rt*16+m

    for (int kb = 0; kb < 1024; kb += 32) {
        bf16x8 bfrag = cvt8(Brow + kb);
#pragma unroll
        for (int rt = 0; rt < 4; rt++) {
            bf16x8 afrag = cvt8(Arow + rt * 8388608 + kb);  // rt*16*512*1024
            acc[rt] = __builtin_amdgcn_mfma_f32_16x16x32_bf16(afrag, bfrag, acc[rt], 0, 0, 0);
        }
    }

    const float bias = bih[col] + bhh[col];
    __bf16* pgt = PG + (long)t * 262144;   // 64*4096
#pragma unroll
    for (int rt = 0; rt < 4; rt++) {
#pragma unroll
        for (int r = 0; r < 4; r++) {
            int b = rt * 16 + quad * 4 + r;   // C row = quad*4 + reg (verified layout)
            pgt[b * 4096 + col] = (__bf16)(acc[rt][r] + bias);
        }
    }
}

// Device-scope grid barrier over one cell's 64 blocks. Monotonic counter.
__device__ __forceinline__ void gsync(unsigned* bar, unsigned target) {
    __syncthreads();                       // drains this block's stores to L2
    if (threadIdx.x == 0) {
        __threadfence();                   // release: L2 writeback to LLC
        __hip_atomic_fetch_add(bar, 1u, __ATOMIC_RELAXED, __HIP_MEMORY_SCOPE_AGENT);
        while (__hip_atomic_load(bar, __ATOMIC_RELAXED, __HIP_MEMORY_SCOPE_AGENT) < target) { }
        __threadfence();                   // acquire: invalidate L1/L2
    }
    __syncthreads();
}

// Persistent scan: 128 blocks = 2 cells x 64 column-slices (16 cols each).
// Wave w owns K-slice [w*256, w*256+256): Whh slice (64 gate rows x 256 K)
// held in 128 VGPRs as bf16 for ALL 512 steps. Cross-wave reduce via LDS.
// c state in registers. h ping-pongs in global bf16 with one barrier/step.
__global__ __launch_bounds__(256, 1) void k_scan(
    const __bf16* __restrict__ PG, const float* __restrict__ Whh,
    const float* __restrict__ c0f, const float* __restrict__ c0b,
    __bf16* __restrict__ buf0, __bf16* __restrict__ buf1,
    float* __restrict__ cf_out, float* __restrict__ cb_out,
    __bf16* __restrict__ h_hist, unsigned* __restrict__ bar)
{
    // [wave][sec][col 16][b 64+4pad] — padded so b128 writes / b32 reads are ~2-way
    __shared__ __align__(16) float gbuf[4][4][16][68];   // 69,632 B

    const int cell = blockIdx.x >> 6;
    const int j0   = (blockIdx.x & 63) * 16;
    const int w    = threadIdx.x >> 6;
    const int lane = threadIdx.x & 63;
    const int m    = lane & 15;
    const int quad = lane >> 4;
    const int kofs = w * 256 + quad * 8;   // this wave's K-slice + quad offset

    // ---- one-time: Whh (fp32) -> bf16 register tiles: [sec][kbi], 128 VGPRs
    bf16x8 Breg[4][8];
#pragma unroll
    for (int sec = 0; sec < 4; sec++) {
        const float* bp = Whh + (sec * 1024 + j0 + m) * 1024 + kofs;
#pragma unroll
        for (int kbi = 0; kbi < 8; kbi++)
            Breg[sec][kbi] = cvt8(bp + kbi * 32);
    }

    // ---- c state in registers (read initial c directly from inputs)
    const float* c0 = cell ? c0b : c0f;
    float c_reg[4];
    int eb[4], ej[4];
#pragma unroll
    for (int k = 0; k < 4; k++) {
        int e = threadIdx.x + k * 256;
        eb[k] = e >> 4; ej[k] = e & 15;
        c_reg[k] = c0[eb[k] * 1024 + j0 + ej[k]];
    }

    unsigned* mybar = bar + cell * 32;   // independent barrier per cell

    for (int t = 0; t < 512; t++) {
        const __bf16* h_in  = ((t & 1) ? buf1 : buf0) + cell * 65536;
        __bf16*       h_out = ((t & 1) ? buf0 : buf1) + cell * 65536;
        const int t_pg = cell ? (511 - t) : t;
        const __bf16* pgt = PG + (long)t_pg * 262144;

        // PG loads first (independent of h) — latency hides under MFMA phase
        float pgv[4][4];
#pragma unroll
        for (int k = 0; k < 4; k++) {
            const int gcb = eb[k] * 4096 + j0 + ej[k];
#pragma unroll
            for (int sec = 0; sec < 4; sec++)
                pgv[k][sec] = (float)pgt[gcb + sec * 1024];
        }

        // ---- MFMA phase: this wave's K-slice, A from global (disjoint per wave)
        f32x4 acc[4][4] = {};   // [sec][rt]
        const __bf16* Ab = h_in + m * 1024 + kofs;
#pragma unroll
        for (int kbi = 0; kbi < 8; kbi++) {
            bf16x8 a0 = *(const bf16x8*)(Ab + kbi * 32);
            bf16x8 a1 = *(const bf16x8*)(Ab + 16384 + kbi * 32);
            bf16x8 a2 = *(const bf16x8*)(Ab + 32768 + kbi * 32);
            bf16x8 a3 = *(const bf16x8*)(Ab + 49152 + kbi * 32);
#pragma unroll
            for (int sec = 0; sec < 4; sec++) {
                acc[sec][0] = __builtin_amdgcn_mfma_f32_16x16x32_bf16(a0, Breg[sec][kbi], acc[sec][0], 0, 0, 0);
                acc[sec][1] = __builtin_amdgcn_mfma_f32_16x16x32_bf16(a1, Breg[sec][kbi], acc[sec][1], 0, 0, 0);
                acc[sec][2] = __builtin_amdgcn_mfma_f32_16x16x32_bf16(a2, Breg[sec][kbi], acc[sec][2], 0, 0, 0);
                acc[sec][3] = __builtin_amdgcn_mfma_f32_16x16x32_bf16(a3, Breg[sec][kbi], acc[sec][3], 0, 0, 0);
            }
        }

        // ---- partials to LDS: acc[sec][rt][r] is (b = rt*16+quad*4+r, col = m)
#pragma unroll
        for (int sec = 0; sec < 4; sec++)
#pragma unroll
            for (int rt = 0; rt < 4; rt++)
                *(f32x4*)&gbuf[w][sec][m][rt * 16 + quad * 4] = acc[sec][rt];
        __syncthreads();

        // ---- reduce over waves + fused LSTM cell
#pragma unroll
        for (int k = 0; k < 4; k++) {
            const int b = eb[k], jj = ej[k];
            float g0 = pgv[k][0] + gbuf[0][0][jj][b] + gbuf[1][0][jj][b] + gbuf[2][0][jj][b] + gbuf[3][0][jj][b];
            float g1 = pgv[k][1] + gbuf[0][1][jj][b] + gbuf[1][1][jj][b] + gbuf[2][1][jj][b] + gbuf[3][1][jj][b];
            float g2 = pgv[k][2] + gbuf[0][2][jj][b] + gbuf[1][2][jj][b] + gbuf[2][2][jj][b] + gbuf[3][2][jj][b];
            float g3 = pgv[k][3] + gbuf[0][3][jj][b] + gbuf[1][3][jj][b] + gbuf[2][3][jj][b] + gbuf[3][3][jj][b];
            const float ig = 1.0f / (1.0f + __expf(-g0));
            const float fg = 1.0f / (1.0f + __expf(-g1));
            const float gv = 2.0f / (1.0f + __expf(-2.0f * g2)) - 1.0f;   // tanh
            const float og = 1.0f / (1.0f + __expf(-g3));
            const float cn = fg * c_reg[k] + ig * gv;
            c_reg[k] = cn;
            const float hn = og * (2.0f / (1.0f + __expf(-2.0f * cn)) - 1.0f);
            const __bf16 hq = (__bf16)hn;
            h_out[b * 1024 + j0 + jj] = hq;
            if (cell == 0) h_hist[((t << 6) + b) * 1024 + j0 + jj] = hq;
        }

        if (t < 511) gsync(mybar, 64u * (unsigned)(t + 1));
    }

    float* c_out = cell ? cb_out : cf_out;
#pragma unroll
    for (int k = 0; k < 4; k++)
        c_out[eb[k] * 1024 + j0 + ej[k]] = c_reg[k];
}

// output[b][t][j] = h_hist[t][b][j]; output[b][t][1024+j] = h_hist[t][63-b][j]
__global__ __launch_bounds__(256) void k_finalize(const __bf16* __restrict__ h_hist,
                                                  float* __restrict__ out) {
    int n = blockIdx.x * 256 + threadIdx.x;   // 4,194,304 threads x 8 j
    int j = (n & 127) * 8;
    int b = (n >> 7) & 63;
    int t = n >> 13;
    bf16x8 hf = *(const bf16x8*)(h_hist + ((t * 64 + b) << 10) + j);
    bf16x8 hr = *(const bf16x8*)(h_hist + ((t * 64 + (63 - b)) << 10) + j);
    float* o = out + (b * 512 + t) * 2048 + j;
#pragma unroll
    for (int k = 0; k < 8; k++) {
        o[k]        = (float)hf[k];
        o[1024 + k] = (float)hr[k];
    }
}

// h_i = concat(hf_final, hb_final), c_i = concat(cf, cb) at out+67108864 / +131072
__global__ __launch_bounds__(256) void k_tail(
    const __bf16* __restrict__ hf_fin, const __bf16* __restrict__ hb_fin,
    const float* __restrict__ cf, const float* __restrict__ cb,
    float* __restrict__ out)
{
    int n = blockIdx.x * 256 + threadIdx.x;   // 16384 threads x 8
    int j = (n & 255) * 8;
    int b = n >> 8;
    float* hi = out + 67108864 + b * 2048 + j;
    float* ci = hi + 131072;
    if (j < 1024) {
        bf16x8 h = *(const bf16x8*)(hf_fin + b * 1024 + j);
#pragma unroll
        for (int k = 0; k < 8; k++) { hi[k] = (float)h[k]; ci[k] = cf[b * 1024 + j + k]; }
    } else {
        int jj = j - 1024;
        bf16x8 h = *(const bf16x8*)(hb_fin + b * 1024 + jj);
#pragma unroll
        for (int k = 0; k < 8; k++) { hi[k] = (float)h[k]; ci[k] = cb[b * 1024 + jj + k]; }
    }
}

extern "C" void kernel_launch(void* const* d_in, const int* in_sizes, int n_in,
                              void* d_out, int out_size, void* d_ws, size_t ws_size,
                              hipStream_t stream) {
    const float* x    = (const float*)d_in[0];
    const float* Wih  = (const float*)d_in[1];
    const float* Whh  = (const float*)d_in[2];
    const float* bih  = (const float*)d_in[3];
    const float* bhh  = (const float*)d_in[4];
    // d_in[5..8] (backward weights) are unused by the reference (it passes the
    // forward weights to both cells).
    const float* h0f  = (const float*)d_in[9];
    const float* c0f  = (const float*)d_in[10];
    const float* h0b  = (const float*)d_in[11];
    const float* c0b  = (const float*)d_in[12];

    float*  out = (float*)d_out;
    __bf16* PG  = (__bf16*)d_out;   // first 256 MiB of d_out reused as PG scratch

    const size_t HHIST_B = 67108864;   // 512*64*1024 bf16
    const size_t NEEDED  = HHIST_B + 4 * 262144 + 256;  // ~65 MiB
    if (ws_size < NEEDED) return;      // loud fail (absmax), no OOB

    char* ws = (char*)d_ws;
    __bf16*   h_hist = (__bf16*)ws;
    __bf16*   buf0   = (__bf16*)(ws + HHIST_B);     // 2 cells x 64 x 1024
    __bf16*   buf1   = buf0 + 131072;
    float*    cf     = (float*)(buf1 + 131072);
    float*    cb     = cf + 65536;
    unsigned* bar    = (unsigned*)(cb + 65536);

    k_init<<<256, 256, 0, stream>>>(h0f, h0b, buf0, bar);
    k_pregemm<<<dim3(64, 512), 256, 0, stream>>>(x, Wih, bih, bhh, PG);
    k_scan<<<128, 256, 0, stream>>>(PG, Whh, c0f, c0b, buf0, buf1, cf, cb, h_hist, bar);
    // after 512 steps (even count): final h for both cells is in buf0
    k_finalize<<<16384, 256, 0, stream>>>(h_hist, out);
    k_tail<<<64, 256, 0, stream>>>(buf0, buf0 + 65536, cf, cb, out);
}